// Round 4
// baseline (661.269 us; speedup 1.0000x reference)
//
#include <hip/hip_runtime.h>
#include <float.h>

// VectorQuantizerEMA: ze (32,64,2048) f32, codebook (1024,64) f32
#define B_   32
#define D_   64
#define TP_  2048
#define K_   1024
#define N_   (B_ * TP_)          // 65536 rows
#define BETA_ 0.25f

// ws layout (float units):
//   [0,1024)    : nc2[k] = np-replicated f32 ||c_k||^2 (pairwise-8 sum)
//   [1024]      : commit-loss accumulator (float, atomic)
//   [1025]      : ambiguous-row count (unsigned, atomic)
//   [1088,2112) : histogram (unsigned, atomic)
//   [2112,...)  : ambiguous list, u32 entries: (row<<10)|guess
#define WS_SC2   0
#define WS_LOSS  1024
#define WS_CNT   1025
#define WS_HIST  1088
#define WS_LIST  2112
#define CAP_     16384

// ambiguity margin: grid rounding (2*ulp(64)=1.5e-5) + ref dot err (~2e-6)
// + our fine-pass err (~1e-6) << 2.5e-4. Expected flagged rows ~100.
#define MARGIN_  2.5e-4f

// ---------------- init: np-replicated ||c||^2, zero hist/loss/cnt -----------
__global__ void vq_init(const float* __restrict__ cb, float* __restrict__ ws) {
    int k = blockIdx.x * blockDim.x + threadIdx.x;
    if (k < K_) {
        const float* c = cb + (size_t)k * D_;
        // numpy pairwise-8: r[j]=p[j]; r[j]+=p[8i+j]; ((r0+r1)+(r2+r3))+((r4+r5)+(r6+r7))
        float r[8];
#pragma unroll
        for (int j = 0; j < 8; ++j) r[j] = c[j] * c[j];
#pragma unroll
        for (int i = 1; i < 8; ++i)
#pragma unroll
            for (int j = 0; j < 8; ++j) { float v = c[8 * i + j]; r[j] += v * v; }
        ws[WS_SC2 + k] = ((r[0] + r[1]) + (r[2] + r[3])) + ((r[4] + r[5]) + (r[6] + r[7]));
        reinterpret_cast<unsigned*>(ws + WS_HIST)[k] = 0u;
        if (k == 0) {
            ws[WS_LOSS] = 0.f;
            reinterpret_cast<unsigned*>(ws)[WS_CNT] = 0u;
        }
    }
}

// ---------------- main: fast f32 argmin + outputs + flag ambiguous ----------
// __launch_bounds__(256, 4): 4 waves/EU min -> VGPR cap 128. Working set is
// x[64] + 16 load regs + 4 accum + addr ~= 100 VGPR. Without this the backend
// capped at 44 VGPR and spilled x[]+accumulators to scratch (R3: FETCH 10.4 GB,
// WRITE 17.5 GB, 972 us).
__global__ __launch_bounds__(256, 4) void vq_main(const float* __restrict__ ze,
                                                  const float* __restrict__ cb,
                                                  float* __restrict__ out,
                                                  float* __restrict__ ws) {
    __shared__ unsigned lhist[K_];
    const int tid = threadIdx.x;
#pragma unroll
    for (int i = tid; i < K_; i += 256) lhist[i] = 0u;

    const int n  = blockIdx.x * 256 + tid;
    const int b  = n >> 11;
    const int tp = n & (TP_ - 1);

    const float* zp = ze + (size_t)b * D_ * TP_ + tp;
    float x[D_];
#pragma unroll
    for (int d = 0; d < D_; ++d) x[d] = zp[(size_t)d * TP_];

    const float4* cb4 = reinterpret_cast<const float4*>(cb);
    const float*  sc2 = ws + WS_SC2;

    float best  = 3.4e38f;
    float best2 = 3.4e38f;
    int   bidx  = 0;

    for (int k0 = 0; k0 < K_; k0 += 4) {
        const float4* p0 = cb4 + (size_t)(k0 + 0) * (D_ / 4);
        const float4* p1 = cb4 + (size_t)(k0 + 1) * (D_ / 4);
        const float4* p2 = cb4 + (size_t)(k0 + 2) * (D_ / 4);
        const float4* p3 = cb4 + (size_t)(k0 + 3) * (D_ / 4);
        float d0 = 0.f, d1 = 0.f, d2 = 0.f, d3 = 0.f;
#pragma unroll
        for (int j = 0; j < D_ / 4; ++j) {
            float4 a = p0[j], bb = p1[j], c = p2[j], dd = p3[j];
            d0 = fmaf(x[4 * j + 0], a.x, d0);
            d0 = fmaf(x[4 * j + 1], a.y, d0);
            d0 = fmaf(x[4 * j + 2], a.z, d0);
            d0 = fmaf(x[4 * j + 3], a.w, d0);
            d1 = fmaf(x[4 * j + 0], bb.x, d1);
            d1 = fmaf(x[4 * j + 1], bb.y, d1);
            d1 = fmaf(x[4 * j + 2], bb.z, d1);
            d1 = fmaf(x[4 * j + 3], bb.w, d1);
            d2 = fmaf(x[4 * j + 0], c.x, d2);
            d2 = fmaf(x[4 * j + 1], c.y, d2);
            d2 = fmaf(x[4 * j + 2], c.z, d2);
            d2 = fmaf(x[4 * j + 3], c.w, d2);
            d3 = fmaf(x[4 * j + 0], dd.x, d3);
            d3 = fmaf(x[4 * j + 1], dd.y, d3);
            d3 = fmaf(x[4 * j + 2], dd.z, d3);
            d3 = fmaf(x[4 * j + 3], dd.w, d3);
        }
        float v0 = sc2[k0 + 0] - 2.f * d0;
        float v1 = sc2[k0 + 1] - 2.f * d1;
        float v2 = sc2[k0 + 2] - 2.f * d2;
        float v3 = sc2[k0 + 3] - 2.f * d3;
        if (v0 < best) { best2 = best; best = v0; bidx = k0 + 0; } else if (v0 < best2) best2 = v0;
        if (v1 < best) { best2 = best; best = v1; bidx = k0 + 1; } else if (v1 < best2) best2 = v1;
        if (v2 < best) { best2 = best; best = v2; bidx = k0 + 2; } else if (v2 < best2) best2 = v2;
        if (v3 < best) { best2 = best; best = v3; bidx = k0 + 3; } else if (v3 < best2) best2 = v3;
    }

    // ambiguous vs the reference's coarse (+||x||^2) grid -> defer to fixup kernel
    if (best2 - best < MARGIN_) {
        unsigned slot = atomicAdd(reinterpret_cast<unsigned*>(ws) + WS_CNT, 1u);
        if (slot < CAP_)
            reinterpret_cast<unsigned*>(ws + WS_LIST)[slot] =
                ((unsigned)n << 10) | (unsigned)bidx;
    }

    __syncthreads();
    atomicAdd(&lhist[bidx], 1u);

    const float4* q4 = cb4 + (size_t)bidx * (D_ / 4);
    float* o0 = out + (size_t)b * D_ * TP_ + tp;
    float lsum = 0.f;
#pragma unroll
    for (int j = 0; j < D_ / 4; ++j) {
        float4 q = q4[j];
        float qv[4] = {q.x, q.y, q.z, q.w};
#pragma unroll
        for (int c = 0; c < 4; ++c) {
            int   d   = 4 * j + c;
            float zev = x[d];
            o0[(size_t)d * TP_] = qv[c];               // ze + (zq - ze) == zq
            float diff = zev - qv[c];
            lsum = fmaf(diff, diff, lsum);
        }
    }
    out[(size_t)N_ * D_ + n] = (float)bidx;

#pragma unroll
    for (int m = 32; m >= 1; m >>= 1) lsum += __shfl_xor(lsum, m, 64);
    if ((tid & 63) == 0) atomicAdd(ws + WS_LOSS, lsum);

    __syncthreads();
    unsigned* gh = reinterpret_cast<unsigned*>(ws + WS_HIST);
#pragma unroll
    for (int i = tid; i < K_; i += 256) {
        unsigned c = lhist[i];
        if (c) atomicAdd(&gh[i], c);
    }
}

// ---------------- fixup: replicate ref grid argmin for ambiguous rows -------
// one wave per row; lane handles 16 codes; first-index tie-break via packed min
__global__ __launch_bounds__(256, 2) void vq_fix(const float* __restrict__ ze,
                                                 const float* __restrict__ cb,
                                                 float* __restrict__ out,
                                                 float* __restrict__ ws) {
    const int lane = threadIdx.x & 63;
    const unsigned w = blockIdx.x * 4 + (threadIdx.x >> 6);   // wave id, 256 total
    unsigned cnt = reinterpret_cast<const unsigned*>(ws)[WS_CNT];
    if (cnt > CAP_) cnt = CAP_;
    const unsigned* list = reinterpret_cast<const unsigned*>(ws + WS_LIST);
    const float* sc2 = ws + WS_SC2;
    unsigned* gh = reinterpret_cast<unsigned*>(ws + WS_HIST);

    for (unsigned i = w; i < cnt; i += 256) {
        unsigned e = list[i];
        const int n     = (int)(e >> 10);
        const int guess = (int)(e & 1023u);
        const int b  = n >> 11;
        const int tp = n & (TP_ - 1);
        const float* zp = ze + (size_t)b * D_ * TP_ + tp;    // wave-uniform

        float xr[D_];
#pragma unroll
        for (int j = 0; j < D_; ++j) xr[j] = zp[(size_t)j * TP_];

        // np pairwise-8 ||x||^2 (bit-exact replication of np.sum(x*x, axis=1))
        float r[8];
#pragma unroll
        for (int j = 0; j < 8; ++j) r[j] = xr[j] * xr[j];
#pragma unroll
        for (int ii = 1; ii < 8; ++ii)
#pragma unroll
            for (int j = 0; j < 8; ++j) { float v = xr[8 * ii + j]; r[j] += v * v; }
        float nx2 = ((r[0] + r[1]) + (r[2] + r[3])) + ((r[4] + r[5]) + (r[6] + r[7]));

        // 16 codes per lane: dist = fl(fl(nx2+nc2) - 2*fl64->32(dot))
        unsigned long long m = ~0ull;
        const int kbase = lane * 16;
#pragma unroll 1
        for (int kk = 0; kk < 16; ++kk) {
            const int k = kbase + kk;
            const float* cp = cb + (size_t)k * D_;
            double acc = 0.0;
#pragma unroll
            for (int j = 0; j < D_; ++j)
                acc = fma((double)xr[j], (double)cp[j], acc);
            float dotf = (float)acc;
            float A    = nx2 + sc2[k];
            float dist = A - 2.0f * dotf;
            unsigned long long pk =
                ((unsigned long long)__float_as_uint(dist) << 32) | (unsigned)k;
            if (pk < m) m = pk;
        }
#pragma unroll
        for (int s = 32; s >= 1; s >>= 1) {
            unsigned long long o = __shfl_xor(m, s, 64);
            if (o < m) m = o;
        }
        const int gk = (int)(m & 0xFFFFFFFFull);

        if (gk != guess) {
            // patch zq row
            out[(size_t)b * D_ * TP_ + (size_t)lane * TP_ + tp] = cb[(size_t)gk * D_ + lane];
            // loss delta
            float xl = zp[(size_t)lane * TP_];
            float dn = xl - cb[(size_t)gk * D_ + lane];
            float dq = xl - cb[(size_t)guess * D_ + lane];
            float t  = dn * dn - dq * dq;
#pragma unroll
            for (int s = 32; s >= 1; s >>= 1) t += __shfl_xor(t, s, 64);
            if (lane == 0) {
                atomicAdd(ws + WS_LOSS, t);
                out[(size_t)N_ * D_ + n] = (float)gk;
                atomicSub(&gh[guess], 1u);
                atomicAdd(&gh[gk], 1u);
            }
        }
    }
}

// ---------------- finalize: scalars ----------------
__global__ void vq_fin(const float* __restrict__ ws, float* __restrict__ out) {
    __shared__ double red[K_];
    const int t = threadIdx.x;
    const unsigned* gh = reinterpret_cast<const unsigned*>(ws + WS_HIST);
    double p = (double)gh[t] * (1.0 / (double)N_);
    red[t] = -p * log(p + 1e-10);
    __syncthreads();
    for (int s = 512; s > 0; s >>= 1) {
        if (t < s) red[t] += red[t + s];
        __syncthreads();
    }
    if (t == 0) {
        out[(size_t)N_ * D_ + N_]     = BETA_ * ws[WS_LOSS] * (1.0f / (float)(N_ * D_));
        out[(size_t)N_ * D_ + N_ + 1] = (float)exp(red[0]);
    }
}

extern "C" void kernel_launch(void* const* d_in, const int* in_sizes, int n_in,
                              void* d_out, int out_size, void* d_ws, size_t ws_size,
                              hipStream_t stream) {
    const float* ze = (const float*)d_in[0];
    const float* cb = (const float*)d_in[1];
    float* out = (float*)d_out;
    float* ws  = (float*)d_ws;

    vq_init<<<dim3((K_ + 255) / 256), dim3(256), 0, stream>>>(cb, ws);
    vq_main<<<dim3(N_ / 256), dim3(256), 0, stream>>>(ze, cb, out, ws);
    vq_fix<<<dim3(64), dim3(256), 0, stream>>>(ze, cb, out, ws);
    vq_fin<<<dim3(1), dim3(K_), 0, stream>>>(ws, out);
}

// Round 5
// 649.952 us; speedup vs baseline: 1.0174x; 1.0174x over previous
//
#include <hip/hip_runtime.h>
#include <float.h>

// VectorQuantizerEMA: ze (32,64,2048) f32, codebook (1024,64) f32
#define B_   32
#define D_   64
#define TP_  2048
#define K_   1024
#define N_   (B_ * TP_)          // 65536 rows
#define BETA_ 0.25f

// ws layout (float units):
//   [0,1024)    : nc2[k] = np-replicated f32 ||c_k||^2 (pairwise-8 sum)
//   [1024]      : commit-loss accumulator (float, atomic)
//   [1025]      : ambiguous-row count (unsigned, atomic)
//   [1088,2112) : histogram (unsigned, atomic)
//   [2112,...)  : ambiguous list, u32 entries: (row<<10)|guess
#define WS_SC2   0
#define WS_LOSS  1024
#define WS_CNT   1025
#define WS_HIST  1088
#define WS_LIST  2112
#define CAP_     16384

// ambiguity margin: grid rounding (2*ulp(64)=1.5e-5) + ref dot err (~2e-6)
// + our fine-pass err (~1e-6) << 2.5e-4. Expected flagged rows ~100.
#define MARGIN_  2.5e-4f

// ---------------- init: np-replicated ||c||^2, zero hist/loss/cnt -----------
__global__ void vq_init(const float* __restrict__ cb, float* __restrict__ ws) {
    int k = blockIdx.x * blockDim.x + threadIdx.x;
    if (k < K_) {
        const float* c = cb + (size_t)k * D_;
        // numpy pairwise-8: r[j]=p[j]; r[j]+=p[8i+j]; ((r0+r1)+(r2+r3))+((r4+r5)+(r6+r7))
        float r[8];
#pragma unroll
        for (int j = 0; j < 8; ++j) r[j] = c[j] * c[j];
#pragma unroll
        for (int i = 1; i < 8; ++i)
#pragma unroll
            for (int j = 0; j < 8; ++j) { float v = c[8 * i + j]; r[j] += v * v; }
        ws[WS_SC2 + k] = ((r[0] + r[1]) + (r[2] + r[3])) + ((r[4] + r[5]) + (r[6] + r[7]));
        reinterpret_cast<unsigned*>(ws + WS_HIST)[k] = 0u;
        if (k == 0) {
            ws[WS_LOSS] = 0.f;
            reinterpret_cast<unsigned*>(ws)[WS_CNT] = 0u;
        }
    }
}

// ---------------- main: fast f32 argmin + outputs + flag ambiguous ----------
// amdgpu_waves_per_eu(4,4): the backend's perf-hint marked this kernel
// memory-bound and wave-limited it to ~11 waves/EU (44 VGPRs), spilling x[64]
// to scratch (R3/R4: FETCH 10.4 GB, WRITE 17.5 GB, 974 us). The max=4 clamps
// the occupancy target -> 128-VGPR budget -> working set (~80) fits, no spill.
__global__ __attribute__((amdgpu_flat_work_group_size(256, 256),
                          amdgpu_waves_per_eu(4, 4)))
void vq_main(const float* __restrict__ ze,
             const float* __restrict__ cb,
             float* __restrict__ out,
             float* __restrict__ ws) {
    __shared__ unsigned lhist[K_];
    const int tid = threadIdx.x;
#pragma unroll
    for (int i = tid; i < K_; i += 256) lhist[i] = 0u;

    const int n  = blockIdx.x * 256 + tid;
    const int b  = n >> 11;
    const int tp = n & (TP_ - 1);

    const float* zp = ze + (size_t)b * D_ * TP_ + tp;
    float x[D_];
#pragma unroll
    for (int d = 0; d < D_; ++d) x[d] = zp[(size_t)d * TP_];

    const float4* cb4 = reinterpret_cast<const float4*>(cb);
    const float*  sc2 = ws + WS_SC2;

    float best  = 3.4e38f;
    float best2 = 3.4e38f;
    int   bidx  = 0;

    for (int k0 = 0; k0 < K_; k0 += 4) {
        const float4* p0 = cb4 + (size_t)(k0 + 0) * (D_ / 4);
        const float4* p1 = cb4 + (size_t)(k0 + 1) * (D_ / 4);
        const float4* p2 = cb4 + (size_t)(k0 + 2) * (D_ / 4);
        const float4* p3 = cb4 + (size_t)(k0 + 3) * (D_ / 4);
        float d0 = 0.f, d1 = 0.f, d2 = 0.f, d3 = 0.f;
#pragma unroll
        for (int j = 0; j < D_ / 4; ++j) {
            float4 a = p0[j], bb = p1[j], c = p2[j], dd = p3[j];
            d0 = fmaf(x[4 * j + 0], a.x, d0);
            d0 = fmaf(x[4 * j + 1], a.y, d0);
            d0 = fmaf(x[4 * j + 2], a.z, d0);
            d0 = fmaf(x[4 * j + 3], a.w, d0);
            d1 = fmaf(x[4 * j + 0], bb.x, d1);
            d1 = fmaf(x[4 * j + 1], bb.y, d1);
            d1 = fmaf(x[4 * j + 2], bb.z, d1);
            d1 = fmaf(x[4 * j + 3], bb.w, d1);
            d2 = fmaf(x[4 * j + 0], c.x, d2);
            d2 = fmaf(x[4 * j + 1], c.y, d2);
            d2 = fmaf(x[4 * j + 2], c.z, d2);
            d2 = fmaf(x[4 * j + 3], c.w, d2);
            d3 = fmaf(x[4 * j + 0], dd.x, d3);
            d3 = fmaf(x[4 * j + 1], dd.y, d3);
            d3 = fmaf(x[4 * j + 2], dd.z, d3);
            d3 = fmaf(x[4 * j + 3], dd.w, d3);
        }
        float v0 = sc2[k0 + 0] - 2.f * d0;
        float v1 = sc2[k0 + 1] - 2.f * d1;
        float v2 = sc2[k0 + 2] - 2.f * d2;
        float v3 = sc2[k0 + 3] - 2.f * d3;
        if (v0 < best) { best2 = best; best = v0; bidx = k0 + 0; } else if (v0 < best2) best2 = v0;
        if (v1 < best) { best2 = best; best = v1; bidx = k0 + 1; } else if (v1 < best2) best2 = v1;
        if (v2 < best) { best2 = best; best = v2; bidx = k0 + 2; } else if (v2 < best2) best2 = v2;
        if (v3 < best) { best2 = best; best = v3; bidx = k0 + 3; } else if (v3 < best2) best2 = v3;
    }

    // ambiguous vs the reference's coarse (+||x||^2) grid -> defer to fixup kernel
    if (best2 - best < MARGIN_) {
        unsigned slot = atomicAdd(reinterpret_cast<unsigned*>(ws) + WS_CNT, 1u);
        if (slot < CAP_)
            reinterpret_cast<unsigned*>(ws + WS_LIST)[slot] =
                ((unsigned)n << 10) | (unsigned)bidx;
    }

    __syncthreads();
    atomicAdd(&lhist[bidx], 1u);

    const float4* q4 = cb4 + (size_t)bidx * (D_ / 4);
    float* o0 = out + (size_t)b * D_ * TP_ + tp;
    float lsum = 0.f;
#pragma unroll
    for (int j = 0; j < D_ / 4; ++j) {
        float4 q = q4[j];
        float qv[4] = {q.x, q.y, q.z, q.w};
#pragma unroll
        for (int c = 0; c < 4; ++c) {
            int   d   = 4 * j + c;
            float zev = x[d];
            o0[(size_t)d * TP_] = qv[c];               // ze + (zq - ze) == zq
            float diff = zev - qv[c];
            lsum = fmaf(diff, diff, lsum);
        }
    }
    out[(size_t)N_ * D_ + n] = (float)bidx;

#pragma unroll
    for (int m = 32; m >= 1; m >>= 1) lsum += __shfl_xor(lsum, m, 64);
    if ((tid & 63) == 0) atomicAdd(ws + WS_LOSS, lsum);

    __syncthreads();
    unsigned* gh = reinterpret_cast<unsigned*>(ws + WS_HIST);
#pragma unroll
    for (int i = tid; i < K_; i += 256) {
        unsigned c = lhist[i];
        if (c) atomicAdd(&gh[i], c);
    }
}

// ---------------- fixup: replicate ref grid argmin for ambiguous rows -------
// one wave per row; lane handles 16 codes; first-index tie-break via packed min
__global__ __attribute__((amdgpu_flat_work_group_size(256, 256),
                          amdgpu_waves_per_eu(2, 2)))
void vq_fix(const float* __restrict__ ze,
            const float* __restrict__ cb,
            float* __restrict__ out,
            float* __restrict__ ws) {
    const int lane = threadIdx.x & 63;
    const unsigned w = blockIdx.x * 4 + (threadIdx.x >> 6);   // wave id, 256 total
    unsigned cnt = reinterpret_cast<const unsigned*>(ws)[WS_CNT];
    if (cnt > CAP_) cnt = CAP_;
    const unsigned* list = reinterpret_cast<const unsigned*>(ws + WS_LIST);
    const float* sc2 = ws + WS_SC2;
    unsigned* gh = reinterpret_cast<unsigned*>(ws + WS_HIST);

    for (unsigned i = w; i < cnt; i += 256) {
        unsigned e = list[i];
        const int n     = (int)(e >> 10);
        const int guess = (int)(e & 1023u);
        const int b  = n >> 11;
        const int tp = n & (TP_ - 1);
        const float* zp = ze + (size_t)b * D_ * TP_ + tp;    // wave-uniform

        float xr[D_];
#pragma unroll
        for (int j = 0; j < D_; ++j) xr[j] = zp[(size_t)j * TP_];

        // np pairwise-8 ||x||^2 (bit-exact replication of np.sum(x*x, axis=1))
        float r[8];
#pragma unroll
        for (int j = 0; j < 8; ++j) r[j] = xr[j] * xr[j];
#pragma unroll
        for (int ii = 1; ii < 8; ++ii)
#pragma unroll
            for (int j = 0; j < 8; ++j) { float v = xr[8 * ii + j]; r[j] += v * v; }
        float nx2 = ((r[0] + r[1]) + (r[2] + r[3])) + ((r[4] + r[5]) + (r[6] + r[7]));

        // 16 codes per lane: dist = fl(fl(nx2+nc2) - 2*fl64->32(dot))
        unsigned long long m = ~0ull;
        const int kbase = lane * 16;
#pragma unroll 1
        for (int kk = 0; kk < 16; ++kk) {
            const int k = kbase + kk;
            const float* cp = cb + (size_t)k * D_;
            double acc = 0.0;
#pragma unroll
            for (int j = 0; j < D_; ++j)
                acc = fma((double)xr[j], (double)cp[j], acc);
            float dotf = (float)acc;
            float A    = nx2 + sc2[k];
            float dist = A - 2.0f * dotf;
            unsigned long long pk =
                ((unsigned long long)__float_as_uint(dist) << 32) | (unsigned)k;
            if (pk < m) m = pk;
        }
#pragma unroll
        for (int s = 32; s >= 1; s >>= 1) {
            unsigned long long o = __shfl_xor(m, s, 64);
            if (o < m) m = o;
        }
        const int gk = (int)(m & 0xFFFFFFFFull);

        if (gk != guess) {
            // patch zq row
            out[(size_t)b * D_ * TP_ + (size_t)lane * TP_ + tp] = cb[(size_t)gk * D_ + lane];
            // loss delta
            float xl = zp[(size_t)lane * TP_];
            float dn = xl - cb[(size_t)gk * D_ + lane];
            float dq = xl - cb[(size_t)guess * D_ + lane];
            float t  = dn * dn - dq * dq;
#pragma unroll
            for (int s = 32; s >= 1; s >>= 1) t += __shfl_xor(t, s, 64);
            if (lane == 0) {
                atomicAdd(ws + WS_LOSS, t);
                out[(size_t)N_ * D_ + n] = (float)gk;
                atomicSub(&gh[guess], 1u);
                atomicAdd(&gh[gk], 1u);
            }
        }
    }
}

// ---------------- finalize: scalars ----------------
__global__ void vq_fin(const float* __restrict__ ws, float* __restrict__ out) {
    __shared__ double red[K_];
    const int t = threadIdx.x;
    const unsigned* gh = reinterpret_cast<const unsigned*>(ws + WS_HIST);
    double p = (double)gh[t] * (1.0 / (double)N_);
    red[t] = -p * log(p + 1e-10);
    __syncthreads();
    for (int s = 512; s > 0; s >>= 1) {
        if (t < s) red[t] += red[t + s];
        __syncthreads();
    }
    if (t == 0) {
        out[(size_t)N_ * D_ + N_]     = BETA_ * ws[WS_LOSS] * (1.0f / (float)(N_ * D_));
        out[(size_t)N_ * D_ + N_ + 1] = (float)exp(red[0]);
    }
}

extern "C" void kernel_launch(void* const* d_in, const int* in_sizes, int n_in,
                              void* d_out, int out_size, void* d_ws, size_t ws_size,
                              hipStream_t stream) {
    const float* ze = (const float*)d_in[0];
    const float* cb = (const float*)d_in[1];
    float* out = (float*)d_out;
    float* ws  = (float*)d_ws;

    vq_init<<<dim3((K_ + 255) / 256), dim3(256), 0, stream>>>(cb, ws);
    vq_main<<<dim3(N_ / 256), dim3(256), 0, stream>>>(ze, cb, out, ws);
    vq_fix<<<dim3(64), dim3(256), 0, stream>>>(ze, cb, out, ws);
    vq_fin<<<dim3(1), dim3(K_), 0, stream>>>(ws, out);
}

// Round 6
// 320.954 us; speedup vs baseline: 2.0603x; 2.0251x over previous
//
#include <hip/hip_runtime.h>

// VectorQuantizerEMA: ze (32,64,2048) f32, codebook (1024,64) f32
#define B_   32
#define D_   64
#define TP_  2048
#define K_   1024
#define N_   (B_ * TP_)          // 65536 rows
#define BETA_ 0.25f

// ws layout (float units):
//   [0,1024)        : nc2[k] = np-replicated f32 ||c_k||^2 (pairwise-8 sum)
//   [1024]          : commit-loss accumulator (float, atomic)
//   [1025]          : ambiguous-row count (unsigned, atomic)
//   [1088,2112)     : histogram (unsigned, atomic)
//   [2112,18496)    : ambiguous list, u32 entries: (row<<10)|guess
//   [18496,51264)   : cbh bf16 table [1024][64] (ushort)
//   [51264,84032)   : cbl bf16 table [1024][64] (ushort)
#define WS_SC2   0
#define WS_LOSS  1024
#define WS_CNT   1025
#define WS_HIST  1088
#define WS_LIST  2112
#define WS_CBH   18496
#define WS_CBL   51264
#define CAP_     16384

// ambiguity margin: ref grid rounding (~1.7e-5) + our split-bf16 MFMA dot err
// (<=7e-5 worst case) -> need > 2*(8.7e-5) = 1.8e-4. 4e-4 gives 2.2x headroom;
// expected flagged rows ~200 (gap density ~7.7/unit).
#define MARGIN_  4e-4f

typedef __attribute__((ext_vector_type(8))) short short8v;   // 8 bf16
typedef __attribute__((ext_vector_type(4))) float float4v;   // C/D frag

static __device__ __forceinline__ unsigned bf16h(float f) {
    unsigned u = __float_as_uint(f);
    return (u + 0x7FFFu + ((u >> 16) & 1u)) >> 16;   // RNE to bf16 (no NaN here)
}

// ---------------- init: np ||c||^2, bf16 split tables, zero hist/loss/cnt ----
__global__ void vq_init(const float* __restrict__ cb, float* __restrict__ ws) {
    int k = blockIdx.x * blockDim.x + threadIdx.x;
    if (k < K_) {
        const float* c = cb + (size_t)k * D_;
        // numpy pairwise-8 sum of squares (bit-exact np.sum(c*c, axis=1))
        float r[8];
#pragma unroll
        for (int j = 0; j < 8; ++j) r[j] = c[j] * c[j];
#pragma unroll
        for (int i = 1; i < 8; ++i)
#pragma unroll
            for (int j = 0; j < 8; ++j) { float v = c[8 * i + j]; r[j] += v * v; }
        ws[WS_SC2 + k] = ((r[0] + r[1]) + (r[2] + r[3])) + ((r[4] + r[5]) + (r[6] + r[7]));

        // bf16 split tables: c = ch + cl + O(2^-18 |c|)
        unsigned short* cbh = reinterpret_cast<unsigned short*>(ws + WS_CBH);
        unsigned short* cbl = reinterpret_cast<unsigned short*>(ws + WS_CBL);
#pragma unroll
        for (int j = 0; j < D_; ++j) {
            float cv = c[j];
            unsigned hu = bf16h(cv);
            float hf = __uint_as_float(hu << 16);
            unsigned lu = bf16h(cv - hf);
            cbh[(size_t)k * D_ + j] = (unsigned short)hu;
            cbl[(size_t)k * D_ + j] = (unsigned short)lu;
        }
        reinterpret_cast<unsigned*>(ws + WS_HIST)[k] = 0u;
        if (k == 0) {
            ws[WS_LOSS] = 0.f;
            reinterpret_cast<unsigned*>(ws)[WS_CNT] = 0u;
        }
    }
}

// ---------------- main: MFMA distance GEMM + argmin + outputs ----------------
// block = 256 thr = 4 waves; wave = 16 rows x 1024 codes; grid = 1024 blocks
// -> 4096 waves = 4 waves/SIMD (R5 showed 1 wave/SIMD was the latency killer).
__global__ __attribute__((amdgpu_flat_work_group_size(256, 256),
                          amdgpu_waves_per_eu(4, 4)))
void vq_main(const float* __restrict__ ze,
             const float* __restrict__ cb,
             float* __restrict__ out,
             float* __restrict__ ws) {
    __shared__ int bidx_sh[64];
    const int tid  = threadIdx.x;
    const int lane = tid & 63;
    const int w    = tid >> 6;
    const int kg   = lane >> 4;        // k-group 0..3
    const int rc   = lane & 15;        // A-row / B-col selector
    const int n0w  = blockIdx.x * 64 + w * 16;   // wave's first row

    // ---- A fragments: x[row=rc][k=s*32+kg*8+e], split to bf16 hi/lo ----
    {
    }
    const int nA = n0w + rc;
    const int bA = nA >> 11, tA = nA & (TP_ - 1);
    const float* zeA = ze + (size_t)bA * (D_ * TP_) + tA;
    short8v ah[2], al[2];
#pragma unroll
    for (int s = 0; s < 2; ++s) {
#pragma unroll
        for (int e = 0; e < 8; ++e) {
            float xv = zeA[(size_t)(s * 32 + kg * 8 + e) * TP_];
            unsigned hu = bf16h(xv);
            float hf = __uint_as_float(hu << 16);
            unsigned lu = bf16h(xv - hf);
            ah[s][e] = (short)hu;
            al[s][e] = (short)lu;
        }
    }

    const unsigned short* cbh = reinterpret_cast<const unsigned short*>(ws + WS_CBH);
    const unsigned short* cbl = reinterpret_cast<const unsigned short*>(ws + WS_CBL);
    const float* sc2 = ws + WS_SC2;

    float best[4]  = {3.4e38f, 3.4e38f, 3.4e38f, 3.4e38f};
    float best2[4] = {3.4e38f, 3.4e38f, 3.4e38f, 3.4e38f};
    int   bidx[4]  = {0, 0, 0, 0};

    for (int tt = 0; tt < K_ / 16; ++tt) {
        const int code = tt * 16 + rc;
        const unsigned short* ph = cbh + (size_t)code * D_ + kg * 8;
        const unsigned short* pl = cbl + (size_t)code * D_ + kg * 8;
        short8v bh0 = *reinterpret_cast<const short8v*>(ph);
        short8v bh1 = *reinterpret_cast<const short8v*>(ph + 32);
        short8v bl0 = *reinterpret_cast<const short8v*>(pl);
        short8v bl1 = *reinterpret_cast<const short8v*>(pl + 32);
        float4v acc = {0.f, 0.f, 0.f, 0.f};
        acc = __builtin_amdgcn_mfma_f32_16x16x32_bf16(ah[0], bh0, acc, 0, 0, 0);
        acc = __builtin_amdgcn_mfma_f32_16x16x32_bf16(ah[1], bh1, acc, 0, 0, 0);
        acc = __builtin_amdgcn_mfma_f32_16x16x32_bf16(ah[0], bl0, acc, 0, 0, 0);
        acc = __builtin_amdgcn_mfma_f32_16x16x32_bf16(ah[1], bl1, acc, 0, 0, 0);
        acc = __builtin_amdgcn_mfma_f32_16x16x32_bf16(al[0], bh0, acc, 0, 0, 0);
        acc = __builtin_amdgcn_mfma_f32_16x16x32_bf16(al[1], bh1, acc, 0, 0, 0);
        const float s2 = sc2[code];
        // C layout (m89): col = lane&15 (this lane's `code`), row = kg*4 + r
#pragma unroll
        for (int r = 0; r < 4; ++r) {
            float v = fmaf(-2.f, acc[r], s2);
            if (v < best[r]) { best2[r] = best[r]; best[r] = v; bidx[r] = code; }
            else if (v < best2[r]) best2[r] = v;
        }
    }

    // reduce (best,best2,idx) across the 16 cols (low 4 lane bits)
#pragma unroll
    for (int r = 0; r < 4; ++r) {
        unsigned fu = __float_as_uint(best[r]);
        fu = (fu & 0x80000000u) ? ~fu : (fu | 0x80000000u);   // order-preserving
        unsigned long long pk = ((unsigned long long)fu << 32) | (unsigned)bidx[r];
        float bf = best[r], b2 = best2[r];
#pragma unroll
        for (int m = 1; m <= 8; m <<= 1) {
            unsigned long long po = __shfl_xor(pk, m, 64);
            float bo  = __shfl_xor(bf, m, 64);
            float b2o = __shfl_xor(b2, m, 64);
            b2 = fminf(fminf(b2, b2o), fmaxf(bf, bo));
            bf = fminf(bf, bo);
            if (po < pk) pk = po;
        }
        best[r] = bf; best2[r] = b2; bidx[r] = (int)(pk & 0x3FFull);
    }

    if (rc == 0) {
        unsigned* gh = reinterpret_cast<unsigned*>(ws + WS_HIST);
#pragma unroll
        for (int r = 0; r < 4; ++r) {
            const int row = kg * 4 + r;          // row within wave tile
            const int n   = n0w + row;
            const int k   = bidx[r];
            out[(size_t)N_ * D_ + n] = (float)k;
            atomicAdd(&gh[k], 1u);
            if (best2[r] - best[r] < MARGIN_) {
                unsigned slot = atomicAdd(reinterpret_cast<unsigned*>(ws) + WS_CNT, 1u);
                if (slot < CAP_)
                    reinterpret_cast<unsigned*>(ws + WS_LIST)[slot] =
                        ((unsigned)n << 10) | (unsigned)k;
            }
            bidx_sh[w * 16 + row] = k;
        }
    }
    __syncthreads();

    // ---- phase2: zq gather-write + commit loss (coalesced over rows) ----
    const int row  = tid & 63;                    // row within block
    const int half = tid >> 6;                    // dim chunk [half*16, +16)
    const int n2 = blockIdx.x * 64 + row;
    const int b2i = n2 >> 11, t2 = n2 & (TP_ - 1);
    const int k2 = bidx_sh[row];
    const float* zer = ze + (size_t)b2i * (D_ * TP_) + t2;
    float* outr = out + (size_t)b2i * (D_ * TP_) + t2;
    const float* cr = cb + (size_t)k2 * D_ + half * 16;
    float lsum = 0.f;
#pragma unroll
    for (int j = 0; j < 16; ++j) {
        const int d = half * 16 + j;
        float q = cr[j];
        outr[(size_t)d * TP_] = q;                // ze + (zq - ze) == zq
        float diff = zer[(size_t)d * TP_] - q;
        lsum = fmaf(diff, diff, lsum);
    }
#pragma unroll
    for (int m = 32; m >= 1; m >>= 1) lsum += __shfl_xor(lsum, m, 64);
    if (lane == 0) atomicAdd(ws + WS_LOSS, lsum);
}

// ---------------- fixup: replicate ref grid argmin for ambiguous rows -------
// one wave per row; lane handles 16 codes; first-index tie-break via packed min
__global__ void vq_fix(const float* __restrict__ ze,
                       const float* __restrict__ cb,
                       float* __restrict__ out,
                       float* __restrict__ ws) {
    const int lane = threadIdx.x & 63;
    const unsigned w = blockIdx.x * 4 + (threadIdx.x >> 6);   // wave id, 256 total
    unsigned cnt = reinterpret_cast<const unsigned*>(ws)[WS_CNT];
    if (cnt > CAP_) cnt = CAP_;
    const unsigned* list = reinterpret_cast<const unsigned*>(ws + WS_LIST);
    const float* sc2 = ws + WS_SC2;
    unsigned* gh = reinterpret_cast<unsigned*>(ws + WS_HIST);

    for (unsigned i = w; i < cnt; i += 256) {
        unsigned e = list[i];
        const int n     = (int)(e >> 10);
        const int guess = (int)(e & 1023u);
        const int b  = n >> 11;
        const int tp = n & (TP_ - 1);
        const float* zp = ze + (size_t)b * D_ * TP_ + tp;    // wave-uniform

        float xr[D_];
#pragma unroll
        for (int j = 0; j < D_; ++j) xr[j] = zp[(size_t)j * TP_];

        // np pairwise-8 ||x||^2 (bit-exact np.sum(x*x, axis=1))
        float r[8];
#pragma unroll
        for (int j = 0; j < 8; ++j) r[j] = xr[j] * xr[j];
#pragma unroll
        for (int ii = 1; ii < 8; ++ii)
#pragma unroll
            for (int j = 0; j < 8; ++j) { float v = xr[8 * ii + j]; r[j] += v * v; }
        float nx2 = ((r[0] + r[1]) + (r[2] + r[3])) + ((r[4] + r[5]) + (r[6] + r[7]));

        // 16 codes per lane: dist = fl(fl(nx2+nc2) - 2*fl64->32(dot))
        unsigned long long m = ~0ull;
        const int kbase = lane * 16;
#pragma unroll 1
        for (int kk = 0; kk < 16; ++kk) {
            const int k = kbase + kk;
            const float* cp = cb + (size_t)k * D_;
            double acc = 0.0;
#pragma unroll
            for (int j = 0; j < D_; ++j)
                acc = fma((double)xr[j], (double)cp[j], acc);
            float dotf = (float)acc;
            float A    = nx2 + sc2[k];
            float dist = A - 2.0f * dotf;
            unsigned long long pk =
                ((unsigned long long)__float_as_uint(dist) << 32) | (unsigned)k;
            if (pk < m) m = pk;
        }
#pragma unroll
        for (int s = 32; s >= 1; s >>= 1) {
            unsigned long long o = __shfl_xor(m, s, 64);
            if (o < m) m = o;
        }
        const int gk = (int)(m & 0xFFFFFFFFull);

        if (gk != guess) {
            out[(size_t)b * D_ * TP_ + (size_t)lane * TP_ + tp] = cb[(size_t)gk * D_ + lane];
            float xl = zp[(size_t)lane * TP_];
            float dn = xl - cb[(size_t)gk * D_ + lane];
            float dq = xl - cb[(size_t)guess * D_ + lane];
            float t  = dn * dn - dq * dq;
#pragma unroll
            for (int s = 32; s >= 1; s >>= 1) t += __shfl_xor(t, s, 64);
            if (lane == 0) {
                atomicAdd(ws + WS_LOSS, t);
                out[(size_t)N_ * D_ + n] = (float)gk;
                atomicSub(&gh[guess], 1u);
                atomicAdd(&gh[gk], 1u);
            }
        }
    }
}

// ---------------- finalize: scalars ----------------
__global__ void vq_fin(const float* __restrict__ ws, float* __restrict__ out) {
    __shared__ double red[K_];
    const int t = threadIdx.x;
    const unsigned* gh = reinterpret_cast<const unsigned*>(ws + WS_HIST);
    double p = (double)gh[t] * (1.0 / (double)N_);
    red[t] = -p * log(p + 1e-10);
    __syncthreads();
    for (int s = 512; s > 0; s >>= 1) {
        if (t < s) red[t] += red[t + s];
        __syncthreads();
    }
    if (t == 0) {
        out[(size_t)N_ * D_ + N_]     = BETA_ * ws[WS_LOSS] * (1.0f / (float)(N_ * D_));
        out[(size_t)N_ * D_ + N_ + 1] = (float)exp(red[0]);
    }
}

extern "C" void kernel_launch(void* const* d_in, const int* in_sizes, int n_in,
                              void* d_out, int out_size, void* d_ws, size_t ws_size,
                              hipStream_t stream) {
    const float* ze = (const float*)d_in[0];
    const float* cb = (const float*)d_in[1];
    float* out = (float*)d_out;
    float* ws  = (float*)d_ws;

    vq_init<<<dim3((K_ + 255) / 256), dim3(256), 0, stream>>>(cb, ws);
    vq_main<<<dim3(N_ / 64), dim3(256), 0, stream>>>(ze, cb, out, ws);
    vq_fix<<<dim3(64), dim3(256), 0, stream>>>(ze, cb, out, ws);
    vq_fin<<<dim3(1), dim3(K_), 0, stream>>>(ws, out);
}

// Round 7
// 318.115 us; speedup vs baseline: 2.0787x; 1.0089x over previous
//
#include <hip/hip_runtime.h>

// VectorQuantizerEMA: ze (32,64,2048) f32, codebook (1024,64) f32
#define B_   32
#define D_   64
#define TP_  2048
#define K_   1024
#define N_   (B_ * TP_)          // 65536 rows
#define BETA_ 0.25f

// ws layout (float units):
//   [0,1024)        : nc2[k] = np-replicated f32 ||c_k||^2 (pairwise-8 sum)
//   [1024]          : commit-loss accumulator (float, atomic)
//   [1025]          : ambiguous-row count (unsigned, atomic)
//   [1088,2112)     : histogram (unsigned, atomic)
//   [2112,18496)    : ambiguous list, u32 entries: (row<<10)|guess
//   [18496,51264)   : cbh bf16 table [1024][64] (ushort)
//   [51264,84032)   : cbl bf16 table [1024][64] (ushort)
#define WS_SC2   0
#define WS_LOSS  1024
#define WS_CNT   1025
#define WS_HIST  1088
#define WS_LIST  2112
#define WS_CBH   18496
#define WS_CBL   51264
#define CAP_     16384

// ambiguity margin: ref grid rounding (~1.7e-5) + split-bf16 MFMA dot err
// (<=7e-5) -> need >1.8e-4; 4e-4 gives 2.2x headroom (~200 flagged rows).
#define MARGIN_  4e-4f

typedef __attribute__((ext_vector_type(8))) short short8v;   // 8 bf16
typedef __attribute__((ext_vector_type(4))) float float4v;   // C/D frag

static __device__ __forceinline__ unsigned bf16h(float f) {
    unsigned u = __float_as_uint(f);
    return (u + 0x7FFFu + ((u >> 16) & 1u)) >> 16;   // RNE to bf16 (no NaN here)
}

// ---------------- init: np ||c||^2, bf16 split tables, zero hist/loss/cnt ----
__global__ void vq_init(const float* __restrict__ cb, float* __restrict__ ws) {
    int k = blockIdx.x * blockDim.x + threadIdx.x;
    if (k < K_) {
        const float* c = cb + (size_t)k * D_;
        float r[8];
#pragma unroll
        for (int j = 0; j < 8; ++j) r[j] = c[j] * c[j];
#pragma unroll
        for (int i = 1; i < 8; ++i)
#pragma unroll
            for (int j = 0; j < 8; ++j) { float v = c[8 * i + j]; r[j] += v * v; }
        ws[WS_SC2 + k] = ((r[0] + r[1]) + (r[2] + r[3])) + ((r[4] + r[5]) + (r[6] + r[7]));

        unsigned short* cbh = reinterpret_cast<unsigned short*>(ws + WS_CBH);
        unsigned short* cbl = reinterpret_cast<unsigned short*>(ws + WS_CBL);
#pragma unroll
        for (int j = 0; j < D_; ++j) {
            float cv = c[j];
            unsigned hu = bf16h(cv);
            float hf = __uint_as_float(hu << 16);
            unsigned lu = bf16h(cv - hf);
            cbh[(size_t)k * D_ + j] = (unsigned short)hu;
            cbl[(size_t)k * D_ + j] = (unsigned short)lu;
        }
        reinterpret_cast<unsigned*>(ws + WS_HIST)[k] = 0u;
        if (k == 0) {
            ws[WS_LOSS] = 0.f;
            reinterpret_cast<unsigned*>(ws)[WS_CNT] = 0u;
        }
    }
}

// ---------------- main: MFMA distance GEMM + argmin + outputs ----------------
// R6: loop was load->wait->mfma->compare serial; every tile paid ~350cy L2
// latency (MfmaUtil 5%). Fix: distance-2 register double-buffer prefetch —
// tile tt+2's loads issue at end of iter tt, in flight across iter tt+1.
__global__ __attribute__((amdgpu_flat_work_group_size(256, 256),
                          amdgpu_waves_per_eu(4, 4)))
void vq_main(const float* __restrict__ ze,
             const float* __restrict__ cb,
             float* __restrict__ out,
             float* __restrict__ ws) {
    __shared__ int bidx_sh[64];
    const int tid  = threadIdx.x;
    const int lane = tid & 63;
    const int w    = tid >> 6;
    const int kg   = lane >> 4;        // k-group 0..3
    const int rc   = lane & 15;        // A-row / B-col selector
    const int n0w  = blockIdx.x * 64 + w * 16;   // wave's first row

    // ---- A fragments: x[row=rc][k=s*32+kg*8+e], split to bf16 hi/lo ----
    const int nA = n0w + rc;
    const int bA = nA >> 11, tA = nA & (TP_ - 1);
    const float* zeA = ze + (size_t)bA * (D_ * TP_) + tA;
    short8v ah[2], al[2];
#pragma unroll
    for (int s = 0; s < 2; ++s) {
#pragma unroll
        for (int e = 0; e < 8; ++e) {
            float xv = zeA[(size_t)(s * 32 + kg * 8 + e) * TP_];
            unsigned hu = bf16h(xv);
            float hf = __uint_as_float(hu << 16);
            unsigned lu = bf16h(xv - hf);
            ah[s][e] = (short)hu;
            al[s][e] = (short)lu;
        }
    }

    const unsigned short* cbh = reinterpret_cast<const unsigned short*>(ws + WS_CBH);
    const unsigned short* cbl = reinterpret_cast<const unsigned short*>(ws + WS_CBL);
    const float* sc2 = ws + WS_SC2;

    // per-lane table base for this lane's (code = tt*16 + rc, kg) slice;
    // tile stride = 16 codes * 64 dims = 1024 shorts
    const unsigned short* ph = cbh + (size_t)rc * D_ + kg * 8;
    const unsigned short* pl = cbl + (size_t)rc * D_ + kg * 8;

    float best[4]  = {3.4e38f, 3.4e38f, 3.4e38f, 3.4e38f};
    float best2[4] = {3.4e38f, 3.4e38f, 3.4e38f, 3.4e38f};
    int   bidx[4]  = {0, 0, 0, 0};

    // double-buffered B fragments, prefetch distance 2
    short8v bh0[2], bh1[2], bl0[2], bl1[2];
    float   s2b[2];
#pragma unroll
    for (int p = 0; p < 2; ++p) {
        const unsigned short* hp = ph + (size_t)p * 1024;
        const unsigned short* lp = pl + (size_t)p * 1024;
        bh0[p] = *reinterpret_cast<const short8v*>(hp);
        bh1[p] = *reinterpret_cast<const short8v*>(hp + 32);
        bl0[p] = *reinterpret_cast<const short8v*>(lp);
        bl1[p] = *reinterpret_cast<const short8v*>(lp + 32);
        s2b[p] = sc2[p * 16 + rc];
    }

#pragma unroll 2
    for (int tt = 0; tt < K_ / 16; ++tt) {
        const int pb = tt & 1;                    // static after unroll-2
        float4v acc = {0.f, 0.f, 0.f, 0.f};
        acc = __builtin_amdgcn_mfma_f32_16x16x32_bf16(ah[0], bh0[pb], acc, 0, 0, 0);
        acc = __builtin_amdgcn_mfma_f32_16x16x32_bf16(ah[1], bh1[pb], acc, 0, 0, 0);
        acc = __builtin_amdgcn_mfma_f32_16x16x32_bf16(ah[0], bl0[pb], acc, 0, 0, 0);
        acc = __builtin_amdgcn_mfma_f32_16x16x32_bf16(ah[1], bl1[pb], acc, 0, 0, 0);
        acc = __builtin_amdgcn_mfma_f32_16x16x32_bf16(al[0], bh0[pb], acc, 0, 0, 0);
        acc = __builtin_amdgcn_mfma_f32_16x16x32_bf16(al[1], bh1[pb], acc, 0, 0, 0);
        const float s2 = s2b[pb];

        // prefetch tile tt+2 into the buffer just consumed (WAR, no copy)
        if (tt < K_ / 16 - 2) {
            const unsigned short* hp = ph + (size_t)(tt + 2) * 1024;
            const unsigned short* lp = pl + (size_t)(tt + 2) * 1024;
            bh0[pb] = *reinterpret_cast<const short8v*>(hp);
            bh1[pb] = *reinterpret_cast<const short8v*>(hp + 32);
            bl0[pb] = *reinterpret_cast<const short8v*>(lp);
            bl1[pb] = *reinterpret_cast<const short8v*>(lp + 32);
            s2b[pb] = sc2[(tt + 2) * 16 + rc];
        }

        const int code = tt * 16 + rc;
        // C layout (m89): col = lane&15 (this lane's `code`), row = kg*4 + r
#pragma unroll
        for (int r = 0; r < 4; ++r) {
            float v = fmaf(-2.f, acc[r], s2);
            if (v < best[r]) { best2[r] = best[r]; best[r] = v; bidx[r] = code; }
            else if (v < best2[r]) best2[r] = v;
        }
    }

    // reduce (best,best2,idx) across the 16 cols (low 4 lane bits)
#pragma unroll
    for (int r = 0; r < 4; ++r) {
        unsigned fu = __float_as_uint(best[r]);
        fu = (fu & 0x80000000u) ? ~fu : (fu | 0x80000000u);   // order-preserving
        unsigned long long pk = ((unsigned long long)fu << 32) | (unsigned)bidx[r];
        float bf = best[r], b2 = best2[r];
#pragma unroll
        for (int m = 1; m <= 8; m <<= 1) {
            unsigned long long po = __shfl_xor(pk, m, 64);
            float bo  = __shfl_xor(bf, m, 64);
            float b2o = __shfl_xor(b2, m, 64);
            b2 = fminf(fminf(b2, b2o), fmaxf(bf, bo));
            bf = fminf(bf, bo);
            if (po < pk) pk = po;
        }
        best[r] = bf; best2[r] = b2; bidx[r] = (int)(pk & 0x3FFull);
    }

    if (rc == 0) {
        unsigned* gh = reinterpret_cast<unsigned*>(ws + WS_HIST);
#pragma unroll
        for (int r = 0; r < 4; ++r) {
            const int row = kg * 4 + r;          // row within wave tile
            const int n   = n0w + row;
            const int k   = bidx[r];
            out[(size_t)N_ * D_ + n] = (float)k;
            atomicAdd(&gh[k], 1u);
            if (best2[r] - best[r] < MARGIN_) {
                unsigned slot = atomicAdd(reinterpret_cast<unsigned*>(ws) + WS_CNT, 1u);
                if (slot < CAP_)
                    reinterpret_cast<unsigned*>(ws + WS_LIST)[slot] =
                        ((unsigned)n << 10) | (unsigned)k;
            }
            bidx_sh[w * 16 + row] = k;
        }
    }
    __syncthreads();

    // ---- phase2: zq gather-write + commit loss (coalesced over rows) ----
    const int row  = tid & 63;                    // row within block
    const int half = tid >> 6;                    // dim chunk [half*16, +16)
    const int n2 = blockIdx.x * 64 + row;
    const int b2i = n2 >> 11, t2 = n2 & (TP_ - 1);
    const int k2 = bidx_sh[row];
    const float* zer = ze + (size_t)b2i * (D_ * TP_) + t2;
    float* outr = out + (size_t)b2i * (D_ * TP_) + t2;
    const float* cr = cb + (size_t)k2 * D_ + half * 16;
    float lsum = 0.f;
#pragma unroll
    for (int j = 0; j < 16; ++j) {
        const int d = half * 16 + j;
        float q = cr[j];
        outr[(size_t)d * TP_] = q;                // ze + (zq - ze) == zq
        float diff = zer[(size_t)d * TP_] - q;
        lsum = fmaf(diff, diff, lsum);
    }
#pragma unroll
    for (int m = 32; m >= 1; m >>= 1) lsum += __shfl_xor(lsum, m, 64);
    if (lane == 0) atomicAdd(ws + WS_LOSS, lsum);
}

// ---------------- fixup: replicate ref grid argmin for ambiguous rows -------
__global__ void vq_fix(const float* __restrict__ ze,
                       const float* __restrict__ cb,
                       float* __restrict__ out,
                       float* __restrict__ ws) {
    const int lane = threadIdx.x & 63;
    const unsigned w = blockIdx.x * 4 + (threadIdx.x >> 6);   // wave id, 256 total
    unsigned cnt = reinterpret_cast<const unsigned*>(ws)[WS_CNT];
    if (cnt > CAP_) cnt = CAP_;
    const unsigned* list = reinterpret_cast<const unsigned*>(ws + WS_LIST);
    const float* sc2 = ws + WS_SC2;
    unsigned* gh = reinterpret_cast<unsigned*>(ws + WS_HIST);

    for (unsigned i = w; i < cnt; i += 256) {
        unsigned e = list[i];
        const int n     = (int)(e >> 10);
        const int guess = (int)(e & 1023u);
        const int b  = n >> 11;
        const int tp = n & (TP_ - 1);
        const float* zp = ze + (size_t)b * D_ * TP_ + tp;    // wave-uniform

        float xr[D_];
#pragma unroll
        for (int j = 0; j < D_; ++j) xr[j] = zp[(size_t)j * TP_];

        float r[8];
#pragma unroll
        for (int j = 0; j < 8; ++j) r[j] = xr[j] * xr[j];
#pragma unroll
        for (int ii = 1; ii < 8; ++ii)
#pragma unroll
            for (int j = 0; j < 8; ++j) { float v = xr[8 * ii + j]; r[j] += v * v; }
        float nx2 = ((r[0] + r[1]) + (r[2] + r[3])) + ((r[4] + r[5]) + (r[6] + r[7]));

        unsigned long long m = ~0ull;
        const int kbase = lane * 16;
#pragma unroll 1
        for (int kk = 0; kk < 16; ++kk) {
            const int k = kbase + kk;
            const float* cp = cb + (size_t)k * D_;
            double acc = 0.0;
#pragma unroll
            for (int j = 0; j < D_; ++j)
                acc = fma((double)xr[j], (double)cp[j], acc);
            float dotf = (float)acc;
            float A    = nx2 + sc2[k];
            float dist = A - 2.0f * dotf;
            unsigned long long pk =
                ((unsigned long long)__float_as_uint(dist) << 32) | (unsigned)k;
            if (pk < m) m = pk;
        }
#pragma unroll
        for (int s = 32; s >= 1; s >>= 1) {
            unsigned long long o = __shfl_xor(m, s, 64);
            if (o < m) m = o;
        }
        const int gk = (int)(m & 0xFFFFFFFFull);

        if (gk != guess) {
            out[(size_t)b * D_ * TP_ + (size_t)lane * TP_ + tp] = cb[(size_t)gk * D_ + lane];
            float xl = zp[(size_t)lane * TP_];
            float dn = xl - cb[(size_t)gk * D_ + lane];
            float dq = xl - cb[(size_t)guess * D_ + lane];
            float t  = dn * dn - dq * dq;
#pragma unroll
            for (int s = 32; s >= 1; s >>= 1) t += __shfl_xor(t, s, 64);
            if (lane == 0) {
                atomicAdd(ws + WS_LOSS, t);
                out[(size_t)N_ * D_ + n] = (float)gk;
                atomicSub(&gh[guess], 1u);
                atomicAdd(&gh[gk], 1u);
            }
        }
    }
}

// ---------------- finalize: scalars ----------------
__global__ void vq_fin(const float* __restrict__ ws, float* __restrict__ out) {
    __shared__ double red[K_];
    const int t = threadIdx.x;
    const unsigned* gh = reinterpret_cast<const unsigned*>(ws + WS_HIST);
    double p = (double)gh[t] * (1.0 / (double)N_);
    red[t] = -p * log(p + 1e-10);
    __syncthreads();
    for (int s = 512; s > 0; s >>= 1) {
        if (t < s) red[t] += red[t + s];
        __syncthreads();
    }
    if (t == 0) {
        out[(size_t)N_ * D_ + N_]     = BETA_ * ws[WS_LOSS] * (1.0f / (float)(N_ * D_));
        out[(size_t)N_ * D_ + N_ + 1] = (float)exp(red[0]);
    }
}

extern "C" void kernel_launch(void* const* d_in, const int* in_sizes, int n_in,
                              void* d_out, int out_size, void* d_ws, size_t ws_size,
                              hipStream_t stream) {
    const float* ze = (const float*)d_in[0];
    const float* cb = (const float*)d_in[1];
    float* out = (float*)d_out;
    float* ws  = (float*)d_ws;

    vq_init<<<dim3((K_ + 255) / 256), dim3(256), 0, stream>>>(cb, ws);
    vq_main<<<dim3(N_ / 64), dim3(256), 0, stream>>>(ze, cb, out, ws);
    vq_fix<<<dim3(64), dim3(256), 0, stream>>>(ze, cb, out, ws);
    vq_fin<<<dim3(1), dim3(K_), 0, stream>>>(ws, out);
}

// Round 8
// 247.031 us; speedup vs baseline: 2.6769x; 1.2878x over previous
//
#include <hip/hip_runtime.h>

// VectorQuantizerEMA: ze (32,64,2048) f32, codebook (1024,64) f32
#define B_   32
#define D_   64
#define TP_  2048
#define K_   1024
#define N_   (B_ * TP_)          // 65536 rows
#define BETA_ 0.25f

// ws layout (float units):
//   [0,1024)        : nc2[k] = np-replicated f32 ||c_k||^2 (pairwise-8 sum)
//   [1024]          : commit-loss accumulator (float, atomic)
//   [1025]          : ambiguous-row count (unsigned, atomic)
//   [1088,2112)     : histogram (unsigned, atomic)
//   [2112,18496)    : ambiguous list, u32 entries: (row<<10)|guess
//   [18496,84032)   : pre-swizzled bf16 split-table image, 32 tiles x 8KB.
//                     tile t = codes [t*32, t*32+32); per tile: 2048 ushorts hi,
//                     2048 ushorts lo; element (r=code&31, dim j) at ushort
//                     idx r*64 + (j ^ ((r&7)<<3))  [16B-chunk XOR swizzle]
#define WS_SC2   0
#define WS_LOSS  1024
#define WS_CNT   1025
#define WS_HIST  1088
#define WS_LIST  2112
#define WS_TBL   18496
#define CAP_     16384

// ambiguity margin: ref grid rounding (~1.7e-5) + split-bf16 MFMA dot err
// (<=7e-5) -> need >1.8e-4; 4e-4 gives 2.2x headroom (~200 flagged rows).
#define MARGIN_  4e-4f

typedef __attribute__((ext_vector_type(8))) short short8v;   // 8 bf16
typedef __attribute__((ext_vector_type(4))) float float4v;   // C/D frag

static __device__ __forceinline__ unsigned bf16h(float f) {
    unsigned u = __float_as_uint(f);
    return (u + 0x7FFFu + ((u >> 16) & 1u)) >> 16;   // RNE to bf16 (no NaN here)
}
static __device__ __forceinline__ int swz(int r, int j) {   // ushort index in a 32x64 half-tile
    return r * 64 + (j ^ ((r & 7) << 3));
}

// ---------------- init: np ||c||^2, swizzled split tables, zero state --------
__global__ void vq_init(const float* __restrict__ cb, float* __restrict__ ws) {
    int k = blockIdx.x * blockDim.x + threadIdx.x;
    if (k < K_) {
        const float* c = cb + (size_t)k * D_;
        float r[8];
#pragma unroll
        for (int j = 0; j < 8; ++j) r[j] = c[j] * c[j];
#pragma unroll
        for (int i = 1; i < 8; ++i)
#pragma unroll
            for (int j = 0; j < 8; ++j) { float v = c[8 * i + j]; r[j] += v * v; }
        ws[WS_SC2 + k] = ((r[0] + r[1]) + (r[2] + r[3])) + ((r[4] + r[5]) + (r[6] + r[7]));

        unsigned short* img = reinterpret_cast<unsigned short*>(ws + WS_TBL);
        unsigned short* tile = img + (size_t)(k >> 5) * 4096;
        const int rr = k & 31;
#pragma unroll
        for (int j = 0; j < D_; ++j) {
            float cv = c[j];
            unsigned hu = bf16h(cv);
            float hf = __uint_as_float(hu << 16);
            unsigned lu = bf16h(cv - hf);
            tile[swz(rr, j)]        = (unsigned short)hu;
            tile[2048 + swz(rr, j)] = (unsigned short)lu;
        }
        reinterpret_cast<unsigned*>(ws + WS_HIST)[k] = 0u;
        if (k == 0) {
            ws[WS_LOSS] = 0.f;
            reinterpret_cast<unsigned*>(ws)[WS_CNT] = 0u;
        }
    }
}

// ---------------- main: LDS-staged MFMA distance GEMM + argmin + outputs -----
// R6/R7: per-lane global B loads paid serialized L2 latency (MfmaUtil 5.5%),
// and source-level register prefetch was defeated by the scheduler. Fix:
// stage 8KB code-tiles into double-buffered LDS via global_load_lds (linear
// dest, pre-swizzled source image) and consume with swizzled ds_read_b128.
__global__ __attribute__((amdgpu_flat_work_group_size(256, 256),
                          amdgpu_waves_per_eu(4, 4)))
void vq_main(const float* __restrict__ ze,
             const float* __restrict__ cb,
             float* __restrict__ out,
             float* __restrict__ ws) {
    __shared__ unsigned short lds[2][4096] __attribute__((aligned(16)));
    __shared__ int bidx_sh[64];
    const int tid  = threadIdx.x;
    const int lane = tid & 63;
    const int w    = tid >> 6;
    const int kg   = lane >> 4;        // k-group 0..3
    const int rc   = lane & 15;        // A-row / B-col selector
    const int n0w  = blockIdx.x * 64 + w * 16;   // wave's first row

    // ---- A fragments: x[row=rc][k=s*32+kg*8+e], split to bf16 hi/lo ----
    const int nA = n0w + rc;
    const int bA = nA >> 11, tA = nA & (TP_ - 1);
    const float* zeA = ze + (size_t)bA * (D_ * TP_) + tA;
    short8v ah[2], al[2];
#pragma unroll
    for (int s = 0; s < 2; ++s) {
#pragma unroll
        for (int e = 0; e < 8; ++e) {
            float xv = zeA[(size_t)(s * 32 + kg * 8 + e) * TP_];
            unsigned hu = bf16h(xv);
            float hf = __uint_as_float(hu << 16);
            unsigned lu = bf16h(xv - hf);
            ah[s][e] = (short)hu;
            al[s][e] = (short)lu;
        }
    }

    const unsigned short* img = reinterpret_cast<const unsigned short*>(ws + WS_TBL);
    const float* sc2 = ws + WS_SC2;

    float best[4]  = {3.4e38f, 3.4e38f, 3.4e38f, 3.4e38f};
    float best2[4] = {3.4e38f, 3.4e38f, 3.4e38f, 3.4e38f};
    int   bidx[4]  = {0, 0, 0, 0};

    // stage tile tt into lds[bufi]: 8KB, 2 x 16B per thread, linear dest
#define STAGE(bufi, tt) do {                                                      \
        const unsigned short* _g = img + (size_t)(tt) * 4096 + (size_t)tid * 8;   \
        __builtin_amdgcn_global_load_lds(                                         \
            (const __attribute__((address_space(1))) unsigned int*)_g,            \
            (__attribute__((address_space(3))) unsigned int*)&lds[bufi][w * 512], \
            16, 0, 0);                                                            \
        __builtin_amdgcn_global_load_lds(                                         \
            (const __attribute__((address_space(1))) unsigned int*)(_g + 2048),   \
            (__attribute__((address_space(3))) unsigned int*)&lds[bufi][2048 + w * 512], \
            16, 0, 0);                                                            \
    } while (0)

    // one 16-code subtile: 4 swizzled ds_read_b128 + 6 MFMA + argmin update
#define SUBTILE(bufi, tt, sub) do {                                               \
        const int r_  = (sub) * 16 + rc;                                          \
        const int cx0 = (kg * 8) ^ ((r_ & 7) << 3);                               \
        const int cx1 = (32 + kg * 8) ^ ((r_ & 7) << 3);                          \
        const unsigned short* bp = &lds[bufi][r_ * 64];                           \
        short8v bh0 = *reinterpret_cast<const short8v*>(bp + cx0);                \
        short8v bh1 = *reinterpret_cast<const short8v*>(bp + cx1);                \
        short8v bl0 = *reinterpret_cast<const short8v*>(bp + 2048 + cx0);         \
        short8v bl1 = *reinterpret_cast<const short8v*>(bp + 2048 + cx1);         \
        float4v acc = {0.f, 0.f, 0.f, 0.f};                                       \
        acc = __builtin_amdgcn_mfma_f32_16x16x32_bf16(ah[0], bh0, acc, 0, 0, 0);  \
        acc = __builtin_amdgcn_mfma_f32_16x16x32_bf16(ah[1], bh1, acc, 0, 0, 0);  \
        acc = __builtin_amdgcn_mfma_f32_16x16x32_bf16(ah[0], bl0, acc, 0, 0, 0);  \
        acc = __builtin_amdgcn_mfma_f32_16x16x32_bf16(ah[1], bl1, acc, 0, 0, 0);  \
        acc = __builtin_amdgcn_mfma_f32_16x16x32_bf16(al[0], bh0, acc, 0, 0, 0);  \
        acc = __builtin_amdgcn_mfma_f32_16x16x32_bf16(al[1], bh1, acc, 0, 0, 0);  \
        const int code = (tt) * 32 + (sub) * 16 + rc;                             \
        const float s2 = sc2[code];                                               \
        _Pragma("unroll")                                                         \
        for (int r = 0; r < 4; ++r) {                                             \
            float v = fmaf(-2.f, acc[r], s2);                                     \
            if (v < best[r]) { best2[r] = best[r]; best[r] = v; bidx[r] = code; } \
            else if (v < best2[r]) best2[r] = v;                                  \
        }                                                                         \
    } while (0)

    STAGE(0, 0);
    __syncthreads();                  // compiler emits vmcnt(0) before s_barrier
    int cur = 0;
    for (int tt = 0; tt < K_ / 32; ++tt) {
        if (tt < K_ / 32 - 1) STAGE(cur ^ 1, tt + 1);
        SUBTILE(cur, tt, 0);
        SUBTILE(cur, tt, 1);
        __syncthreads();              // drains stage loads + guards buffer reuse
        cur ^= 1;
    }
#undef STAGE
#undef SUBTILE

    // reduce (best,best2,idx) across the 16 cols (low 4 lane bits)
#pragma unroll
    for (int r = 0; r < 4; ++r) {
        unsigned fu = __float_as_uint(best[r]);
        fu = (fu & 0x80000000u) ? ~fu : (fu | 0x80000000u);   // order-preserving
        unsigned long long pk = ((unsigned long long)fu << 32) | (unsigned)bidx[r];
        float bf = best[r], b2 = best2[r];
#pragma unroll
        for (int m = 1; m <= 8; m <<= 1) {
            unsigned long long po = __shfl_xor(pk, m, 64);
            float bo  = __shfl_xor(bf, m, 64);
            float b2o = __shfl_xor(b2, m, 64);
            b2 = fminf(fminf(b2, b2o), fmaxf(bf, bo));
            bf = fminf(bf, bo);
            if (po < pk) pk = po;
        }
        best[r] = bf; best2[r] = b2; bidx[r] = (int)(pk & 0x3FFull);
    }

    if (rc == 0) {
        unsigned* gh = reinterpret_cast<unsigned*>(ws + WS_HIST);
#pragma unroll
        for (int r = 0; r < 4; ++r) {
            const int row = kg * 4 + r;          // row within wave tile
            const int n   = n0w + row;
            const int k   = bidx[r];
            out[(size_t)N_ * D_ + n] = (float)k;
            atomicAdd(&gh[k], 1u);
            if (best2[r] - best[r] < MARGIN_) {
                unsigned slot = atomicAdd(reinterpret_cast<unsigned*>(ws) + WS_CNT, 1u);
                if (slot < CAP_)
                    reinterpret_cast<unsigned*>(ws + WS_LIST)[slot] =
                        ((unsigned)n << 10) | (unsigned)k;
            }
            bidx_sh[w * 16 + row] = k;
        }
    }
    __syncthreads();

    // ---- phase2: zq gather-write + commit loss (coalesced over rows) ----
    const int row  = tid & 63;                    // row within block
    const int half = tid >> 6;                    // dim chunk [half*16, +16)
    const int n2 = blockIdx.x * 64 + row;
    const int b2i = n2 >> 11, t2 = n2 & (TP_ - 1);
    const int k2 = bidx_sh[row];
    const float* zer = ze + (size_t)b2i * (D_ * TP_) + t2;
    float* outr = out + (size_t)b2i * (D_ * TP_) + t2;
    const float* cr = cb + (size_t)k2 * D_ + half * 16;
    float lsum = 0.f;
#pragma unroll
    for (int j = 0; j < 16; ++j) {
        const int d = half * 16 + j;
        float q = cr[j];
        outr[(size_t)d * TP_] = q;                // ze + (zq - ze) == zq
        float diff = zer[(size_t)d * TP_] - q;
        lsum = fmaf(diff, diff, lsum);
    }
#pragma unroll
    for (int m = 32; m >= 1; m >>= 1) lsum += __shfl_xor(lsum, m, 64);
    if (lane == 0) atomicAdd(ws + WS_LOSS, lsum);
}

// ---------------- fixup: replicate ref grid argmin for ambiguous rows -------
__global__ void vq_fix(const float* __restrict__ ze,
                       const float* __restrict__ cb,
                       float* __restrict__ out,
                       float* __restrict__ ws) {
    const int lane = threadIdx.x & 63;
    const unsigned w = blockIdx.x * 4 + (threadIdx.x >> 6);   // wave id, 256 total
    unsigned cnt = reinterpret_cast<const unsigned*>(ws)[WS_CNT];
    if (cnt > CAP_) cnt = CAP_;
    const unsigned* list = reinterpret_cast<const unsigned*>(ws + WS_LIST);
    const float* sc2 = ws + WS_SC2;
    unsigned* gh = reinterpret_cast<unsigned*>(ws + WS_HIST);

    for (unsigned i = w; i < cnt; i += 256) {
        unsigned e = list[i];
        const int n     = (int)(e >> 10);
        const int guess = (int)(e & 1023u);
        const int b  = n >> 11;
        const int tp = n & (TP_ - 1);
        const float* zp = ze + (size_t)b * D_ * TP_ + tp;    // wave-uniform

        float xr[D_];
#pragma unroll
        for (int j = 0; j < D_; ++j) xr[j] = zp[(size_t)j * TP_];

        float r[8];
#pragma unroll
        for (int j = 0; j < 8; ++j) r[j] = xr[j] * xr[j];
#pragma unroll
        for (int ii = 1; ii < 8; ++ii)
#pragma unroll
            for (int j = 0; j < 8; ++j) { float v = xr[8 * ii + j]; r[j] += v * v; }
        float nx2 = ((r[0] + r[1]) + (r[2] + r[3])) + ((r[4] + r[5]) + (r[6] + r[7]));

        unsigned long long m = ~0ull;
        const int kbase = lane * 16;
#pragma unroll 1
        for (int kk = 0; kk < 16; ++kk) {
            const int k = kbase + kk;
            const float* cp = cb + (size_t)k * D_;
            double acc = 0.0;
#pragma unroll
            for (int j = 0; j < D_; ++j)
                acc = fma((double)xr[j], (double)cp[j], acc);
            float dotf = (float)acc;
            float A    = nx2 + sc2[k];
            float dist = A - 2.0f * dotf;
            unsigned long long pk =
                ((unsigned long long)__float_as_uint(dist) << 32) | (unsigned)k;
            if (pk < m) m = pk;
        }
#pragma unroll
        for (int s = 32; s >= 1; s >>= 1) {
            unsigned long long o = __shfl_xor(m, s, 64);
            if (o < m) m = o;
        }
        const int gk = (int)(m & 0xFFFFFFFFull);

        if (gk != guess) {
            out[(size_t)b * D_ * TP_ + (size_t)lane * TP_ + tp] = cb[(size_t)gk * D_ + lane];
            float xl = zp[(size_t)lane * TP_];
            float dn = xl - cb[(size_t)gk * D_ + lane];
            float dq = xl - cb[(size_t)guess * D_ + lane];
            float t  = dn * dn - dq * dq;
#pragma unroll
            for (int s = 32; s >= 1; s >>= 1) t += __shfl_xor(t, s, 64);
            if (lane == 0) {
                atomicAdd(ws + WS_LOSS, t);
                out[(size_t)N_ * D_ + n] = (float)gk;
                atomicSub(&gh[guess], 1u);
                atomicAdd(&gh[gk], 1u);
            }
        }
    }
}

// ---------------- finalize: scalars ----------------
__global__ void vq_fin(const float* __restrict__ ws, float* __restrict__ out) {
    __shared__ double red[K_];
    const int t = threadIdx.x;
    const unsigned* gh = reinterpret_cast<const unsigned*>(ws + WS_HIST);
    double p = (double)gh[t] * (1.0 / (double)N_);
    red[t] = -p * log(p + 1e-10);
    __syncthreads();
    for (int s = 512; s > 0; s >>= 1) {
        if (t < s) red[t] += red[t + s];
        __syncthreads();
    }
    if (t == 0) {
        out[(size_t)N_ * D_ + N_]     = BETA_ * ws[WS_LOSS] * (1.0f / (float)(N_ * D_));
        out[(size_t)N_ * D_ + N_ + 1] = (float)exp(red[0]);
    }
}

extern "C" void kernel_launch(void* const* d_in, const int* in_sizes, int n_in,
                              void* d_out, int out_size, void* d_ws, size_t ws_size,
                              hipStream_t stream) {
    const float* ze = (const float*)d_in[0];
    const float* cb = (const float*)d_in[1];
    float* out = (float*)d_out;
    float* ws  = (float*)d_ws;

    vq_init<<<dim3((K_ + 255) / 256), dim3(256), 0, stream>>>(cb, ws);
    vq_main<<<dim3(N_ / 64), dim3(256), 0, stream>>>(ze, cb, out, ws);
    vq_fix<<<dim3(64), dim3(256), 0, stream>>>(ze, cb, out, ws);
    vq_fin<<<dim3(1), dim3(K_), 0, stream>>>(ws, out);
}

// Round 9
// 193.364 us; speedup vs baseline: 3.4198x; 1.2775x over previous
//
#include <hip/hip_runtime.h>

// VectorQuantizerEMA: ze (32,64,2048) f32, codebook (1024,64) f32
#define B_   32
#define D_   64
#define TP_  2048
#define K_   1024
#define N_   (B_ * TP_)          // 65536 rows
#define BETA_ 0.25f

// ws layout (float units):
//   [0,1024)        : nc2[k] = np-replicated f32 ||c_k||^2 (pairwise-8 sum)
//   [1024]          : commit-loss accumulator (float, atomic)
//   [1025]          : ambiguous-row count (unsigned, atomic)
//   [1088,2112)     : histogram (unsigned, atomic)
//   [2112,18496)    : ambiguous list, u32 entries: (row<<10)|guess
//   [18496,84032)   : pre-swizzled bf16 split-table image, 32 tiles x 8KB.
//                     tile t = codes [t*32, t*32+32); per tile: 2048 ushorts hi,
//                     2048 ushorts lo; element (r=code&31, dim j) at ushort
//                     idx r*64 + (j ^ ((r&7)<<3))  [16B-chunk XOR swizzle]
#define WS_SC2   0
#define WS_LOSS  1024
#define WS_CNT   1025
#define WS_HIST  1088
#define WS_LIST  2112
#define WS_TBL   18496
#define CAP_     16384

// ambiguity margin: ref grid rounding (~1.7e-5) + split-bf16 MFMA dot err
// (<=7e-5) -> need >1.8e-4; 4e-4 gives 2.2x headroom (~150 flagged rows).
#define MARGIN_  4e-4f

typedef __attribute__((ext_vector_type(8))) short short8v;   // 8 bf16
typedef __attribute__((ext_vector_type(4))) float float4v;   // C/D frag

static __device__ __forceinline__ unsigned bf16h(float f) {
    unsigned u = __float_as_uint(f);
    return (u + 0x7FFFu + ((u >> 16) & 1u)) >> 16;   // RNE to bf16 (no NaN here)
}
static __device__ __forceinline__ int swz(int r, int j) {   // ushort index in a 32x64 half-tile
    return r * 64 + (j ^ ((r & 7) << 3));
}

// ---------------- init: np ||c||^2, swizzled split tables, zero state --------
__global__ void vq_init(const float* __restrict__ cb, float* __restrict__ ws) {
    int k = blockIdx.x * blockDim.x + threadIdx.x;
    if (k < K_) {
        const float* c = cb + (size_t)k * D_;
        float r[8];
#pragma unroll
        for (int j = 0; j < 8; ++j) r[j] = c[j] * c[j];
#pragma unroll
        for (int i = 1; i < 8; ++i)
#pragma unroll
            for (int j = 0; j < 8; ++j) { float v = c[8 * i + j]; r[j] += v * v; }
        ws[WS_SC2 + k] = ((r[0] + r[1]) + (r[2] + r[3])) + ((r[4] + r[5]) + (r[6] + r[7]));

        unsigned short* img = reinterpret_cast<unsigned short*>(ws + WS_TBL);
        unsigned short* tile = img + (size_t)(k >> 5) * 4096;
        const int rr = k & 31;
#pragma unroll
        for (int j = 0; j < D_; ++j) {
            float cv = c[j];
            unsigned hu = bf16h(cv);
            float hf = __uint_as_float(hu << 16);
            unsigned lu = bf16h(cv - hf);
            tile[swz(rr, j)]        = (unsigned short)hu;
            tile[2048 + swz(rr, j)] = (unsigned short)lu;
        }
        reinterpret_cast<unsigned*>(ws + WS_HIST)[k] = 0u;
        if (k == 0) {
            ws[WS_LOSS] = 0.f;
            reinterpret_cast<unsigned*>(ws)[WS_CNT] = 0u;
        }
    }
}

// ---------------- main: LDS-staged MFMA distance GEMM + argmin + outputs -----
__global__ __attribute__((amdgpu_flat_work_group_size(256, 256),
                          amdgpu_waves_per_eu(4, 4)))
void vq_main(const float* __restrict__ ze,
             const float* __restrict__ cb,
             float* __restrict__ out,
             float* __restrict__ ws) {
    __shared__ unsigned short lds[2][4096] __attribute__((aligned(16)));
    __shared__ int bidx_sh[64];
    const int tid  = threadIdx.x;
    const int lane = tid & 63;
    const int w    = tid >> 6;
    const int kg   = lane >> 4;        // k-group 0..3
    const int rc   = lane & 15;        // A-row / B-col selector
    const int n0w  = blockIdx.x * 64 + w * 16;   // wave's first row

    // ---- A fragments: x[row=rc][k=s*32+kg*8+e], split to bf16 hi/lo ----
    const int nA = n0w + rc;
    const int bA = nA >> 11, tA = nA & (TP_ - 1);
    const float* zeA = ze + (size_t)bA * (D_ * TP_) + tA;
    short8v ah[2], al[2];
#pragma unroll
    for (int s = 0; s < 2; ++s) {
#pragma unroll
        for (int e = 0; e < 8; ++e) {
            float xv = zeA[(size_t)(s * 32 + kg * 8 + e) * TP_];
            unsigned hu = bf16h(xv);
            float hf = __uint_as_float(hu << 16);
            unsigned lu = bf16h(xv - hf);
            ah[s][e] = (short)hu;
            al[s][e] = (short)lu;
        }
    }

    const unsigned short* img = reinterpret_cast<const unsigned short*>(ws + WS_TBL);
    const float* sc2 = ws + WS_SC2;

    float best[4]  = {3.4e38f, 3.4e38f, 3.4e38f, 3.4e38f};
    float best2[4] = {3.4e38f, 3.4e38f, 3.4e38f, 3.4e38f};
    int   bidx[4]  = {0, 0, 0, 0};

    // stage tile tt into lds[bufi]: 8KB, 2 x 16B per thread, linear dest
#define STAGE(bufi, tt) do {                                                      \
        const unsigned short* _g = img + (size_t)(tt) * 4096 + (size_t)tid * 8;   \
        __builtin_amdgcn_global_load_lds(                                         \
            (const __attribute__((address_space(1))) unsigned int*)_g,            \
            (__attribute__((address_space(3))) unsigned int*)&lds[bufi][w * 512], \
            16, 0, 0);                                                            \
        __builtin_amdgcn_global_load_lds(                                         \
            (const __attribute__((address_space(1))) unsigned int*)(_g + 2048),   \
            (__attribute__((address_space(3))) unsigned int*)&lds[bufi][2048 + w * 512], \
            16, 0, 0);                                                            \
    } while (0)

    // one 16-code subtile: 4 swizzled ds_read_b128 + 6 MFMA + argmin update
#define SUBTILE(bufi, tt, sub) do {                                               \
        const int r_  = (sub) * 16 + rc;                                          \
        const int cx0 = (kg * 8) ^ ((r_ & 7) << 3);                               \
        const int cx1 = (32 + kg * 8) ^ ((r_ & 7) << 3);                          \
        const unsigned short* bp = &lds[bufi][r_ * 64];                           \
        short8v bh0 = *reinterpret_cast<const short8v*>(bp + cx0);                \
        short8v bh1 = *reinterpret_cast<const short8v*>(bp + cx1);                \
        short8v bl0 = *reinterpret_cast<const short8v*>(bp + 2048 + cx0);         \
        short8v bl1 = *reinterpret_cast<const short8v*>(bp + 2048 + cx1);         \
        float4v acc = {0.f, 0.f, 0.f, 0.f};                                       \
        acc = __builtin_amdgcn_mfma_f32_16x16x32_bf16(ah[0], bh0, acc, 0, 0, 0);  \
        acc = __builtin_amdgcn_mfma_f32_16x16x32_bf16(ah[1], bh1, acc, 0, 0, 0);  \
        acc = __builtin_amdgcn_mfma_f32_16x16x32_bf16(ah[0], bl0, acc, 0, 0, 0);  \
        acc = __builtin_amdgcn_mfma_f32_16x16x32_bf16(ah[1], bl1, acc, 0, 0, 0);  \
        acc = __builtin_amdgcn_mfma_f32_16x16x32_bf16(al[0], bh0, acc, 0, 0, 0);  \
        acc = __builtin_amdgcn_mfma_f32_16x16x32_bf16(al[1], bh1, acc, 0, 0, 0);  \
        const int code = (tt) * 32 + (sub) * 16 + rc;                             \
        const float s2 = sc2[code];                                               \
        _Pragma("unroll")                                                         \
        for (int r = 0; r < 4; ++r) {                                             \
            float v = fmaf(-2.f, acc[r], s2);                                     \
            if (v < best[r]) { best2[r] = best[r]; best[r] = v; bidx[r] = code; } \
            else if (v < best2[r]) best2[r] = v;                                  \
        }                                                                         \
    } while (0)

    STAGE(0, 0);
    __syncthreads();                  // compiler emits vmcnt(0) before s_barrier
    int cur = 0;
    for (int tt = 0; tt < K_ / 32; ++tt) {
        if (tt < K_ / 32 - 1) STAGE(cur ^ 1, tt + 1);
        SUBTILE(cur, tt, 0);
        SUBTILE(cur, tt, 1);
        __syncthreads();              // drains stage loads + guards buffer reuse
        cur ^= 1;
    }
#undef STAGE
#undef SUBTILE

    // reduce (best,best2,idx) across the 16 cols (low 4 lane bits)
#pragma unroll
    for (int r = 0; r < 4; ++r) {
        unsigned fu = __float_as_uint(best[r]);
        fu = (fu & 0x80000000u) ? ~fu : (fu | 0x80000000u);   // order-preserving
        unsigned long long pk = ((unsigned long long)fu << 32) | (unsigned)bidx[r];
        float bf = best[r], b2 = best2[r];
#pragma unroll
        for (int m = 1; m <= 8; m <<= 1) {
            unsigned long long po = __shfl_xor(pk, m, 64);
            float bo  = __shfl_xor(bf, m, 64);
            float b2o = __shfl_xor(b2, m, 64);
            b2 = fminf(fminf(b2, b2o), fmaxf(bf, bo));
            bf = fminf(bf, bo);
            if (po < pk) pk = po;
        }
        best[r] = bf; best2[r] = b2; bidx[r] = (int)(pk & 0x3FFull);
    }

    if (rc == 0) {
        unsigned* gh = reinterpret_cast<unsigned*>(ws + WS_HIST);
#pragma unroll
        for (int r = 0; r < 4; ++r) {
            const int row = kg * 4 + r;          // row within wave tile
            const int n   = n0w + row;
            const int k   = bidx[r];
            out[(size_t)N_ * D_ + n] = (float)k;
            atomicAdd(&gh[k], 1u);
            if (best2[r] - best[r] < MARGIN_) {
                unsigned slot = atomicAdd(reinterpret_cast<unsigned*>(ws) + WS_CNT, 1u);
                if (slot < CAP_)
                    reinterpret_cast<unsigned*>(ws + WS_LIST)[slot] =
                        ((unsigned)n << 10) | (unsigned)k;
            }
            bidx_sh[w * 16 + row] = k;
        }
    }
    __syncthreads();

    // ---- phase2: zq gather-write + commit loss (coalesced over rows) ----
    const int row  = tid & 63;                    // row within block
    const int half = tid >> 6;                    // dim chunk [half*16, +16)
    const int n2 = blockIdx.x * 64 + row;
    const int b2i = n2 >> 11, t2 = n2 & (TP_ - 1);
    const int k2 = bidx_sh[row];
    const float* zer = ze + (size_t)b2i * (D_ * TP_) + t2;
    float* outr = out + (size_t)b2i * (D_ * TP_) + t2;
    const float* cr = cb + (size_t)k2 * D_ + half * 16;
    float lsum = 0.f;
#pragma unroll
    for (int j = 0; j < 16; ++j) {
        const int d = half * 16 + j;
        float q = cr[j];
        outr[(size_t)d * TP_] = q;                // ze + (zq - ze) == zq
        float diff = zer[(size_t)d * TP_] - q;
        lsum = fmaf(diff, diff, lsum);
    }
#pragma unroll
    for (int m = 32; m >= 1; m >>= 1) lsum += __shfl_xor(lsum, m, 64);
    if (lane == 0) atomicAdd(ws + WS_LOSS, lsum);
}

// ---------------- fixup: replicate ref grid argmin for ambiguous rows -------
// R8: default occupancy heuristic allocated 44..64 VGPR -> xr[64] spilled to
// scratch; each of the 1024 xr reads per lane became a serial ~300cy scratch
// round-trip (140 us for ~150 rows; FETCH~=WRITE~=3.8MB was the spill traffic).
// waves_per_eu(1,1) -> ~512-VGPR budget, xr stays in registers.
__global__ __attribute__((amdgpu_flat_work_group_size(256, 256),
                          amdgpu_waves_per_eu(1, 1)))
void vq_fix(const float* __restrict__ ze,
            const float* __restrict__ cb,
            float* __restrict__ out,
            float* __restrict__ ws) {
    const int lane = threadIdx.x & 63;
    const unsigned w = blockIdx.x * 4 + (threadIdx.x >> 6);   // wave id, 256 total
    unsigned cnt = reinterpret_cast<const unsigned*>(ws)[WS_CNT];
    if (cnt > CAP_) cnt = CAP_;
    const unsigned* list = reinterpret_cast<const unsigned*>(ws + WS_LIST);
    const float* sc2 = ws + WS_SC2;
    unsigned* gh = reinterpret_cast<unsigned*>(ws + WS_HIST);

    for (unsigned i = w; i < cnt; i += 256) {
        unsigned e = list[i];
        const int n     = (int)(e >> 10);
        const int guess = (int)(e & 1023u);
        const int b  = n >> 11;
        const int tp = n & (TP_ - 1);
        const float* zp = ze + (size_t)b * D_ * TP_ + tp;    // wave-uniform

        float xr[D_];
#pragma unroll
        for (int j = 0; j < D_; ++j) xr[j] = zp[(size_t)j * TP_];

        float r[8];
#pragma unroll
        for (int j = 0; j < 8; ++j) r[j] = xr[j] * xr[j];
#pragma unroll
        for (int ii = 1; ii < 8; ++ii)
#pragma unroll
            for (int j = 0; j < 8; ++j) { float v = xr[8 * ii + j]; r[j] += v * v; }
        float nx2 = ((r[0] + r[1]) + (r[2] + r[3])) + ((r[4] + r[5]) + (r[6] + r[7]));

        unsigned long long m = ~0ull;
        const int kbase = lane * 16;
#pragma unroll 1
        for (int kk = 0; kk < 16; ++kk) {
            const int k = kbase + kk;
            const float* cp = cb + (size_t)k * D_;
            double acc = 0.0;
#pragma unroll
            for (int j = 0; j < D_; ++j)
                acc = fma((double)xr[j], (double)cp[j], acc);
            float dotf = (float)acc;
            float A    = nx2 + sc2[k];
            float dist = A - 2.0f * dotf;
            unsigned long long pk =
                ((unsigned long long)__float_as_uint(dist) << 32) | (unsigned)k;
            if (pk < m) m = pk;
        }
#pragma unroll
        for (int s = 32; s >= 1; s >>= 1) {
            unsigned long long o = __shfl_xor(m, s, 64);
            if (o < m) m = o;
        }
        const int gk = (int)(m & 0xFFFFFFFFull);

        if (gk != guess) {
            out[(size_t)b * D_ * TP_ + (size_t)lane * TP_ + tp] = cb[(size_t)gk * D_ + lane];
            float xl = zp[(size_t)lane * TP_];
            float dn = xl - cb[(size_t)gk * D_ + lane];
            float dq = xl - cb[(size_t)guess * D_ + lane];
            float t  = dn * dn - dq * dq;
#pragma unroll
            for (int s = 32; s >= 1; s >>= 1) t += __shfl_xor(t, s, 64);
            if (lane == 0) {
                atomicAdd(ws + WS_LOSS, t);
                out[(size_t)N_ * D_ + n] = (float)gk;
                atomicSub(&gh[guess], 1u);
                atomicAdd(&gh[gk], 1u);
            }
        }
    }
}

// ---------------- finalize: scalars ----------------
__global__ void vq_fin(const float* __restrict__ ws, float* __restrict__ out) {
    __shared__ double red[K_];
    const int t = threadIdx.x;
    const unsigned* gh = reinterpret_cast<const unsigned*>(ws + WS_HIST);
    double p = (double)gh[t] * (1.0 / (double)N_);
    red[t] = -p * log(p + 1e-10);
    __syncthreads();
    for (int s = 512; s > 0; s >>= 1) {
        if (t < s) red[t] += red[t + s];
        __syncthreads();
    }
    if (t == 0) {
        out[(size_t)N_ * D_ + N_]     = BETA_ * ws[WS_LOSS] * (1.0f / (float)(N_ * D_));
        out[(size_t)N_ * D_ + N_ + 1] = (float)exp(red[0]);
    }
}

extern "C" void kernel_launch(void* const* d_in, const int* in_sizes, int n_in,
                              void* d_out, int out_size, void* d_ws, size_t ws_size,
                              hipStream_t stream) {
    const float* ze = (const float*)d_in[0];
    const float* cb = (const float*)d_in[1];
    float* out = (float*)d_out;
    float* ws  = (float*)d_ws;

    vq_init<<<dim3((K_ + 255) / 256), dim3(256), 0, stream>>>(cb, ws);
    vq_main<<<dim3(N_ / 64), dim3(256), 0, stream>>>(ze, cb, out, ws);
    vq_fix<<<dim3(64), dim3(256), 0, stream>>>(ze, cb, out, ws);
    vq_fin<<<dim3(1), dim3(K_), 0, stream>>>(ws, out);
}